// Round 1
// baseline (461.821 us; speedup 1.0000x reference)
//
#include <hip/hip_runtime.h>
#include <math.h>

#define PI9 (2.0f * 3.14159265358979323846f / 9.0f)

__device__ __forceinline__ float ssp_f(float x) {
  float sp = (x > 0.f) ? (x + log1pf(__expf(-x))) : log1pf(__expf(x));
  return sp - 0.69314718f;
}

// ---------------------------------------------------------------------------
// Precompute C[p,q,d] (stored transposed as CT[d][p][q-padded-to-12]) from
// Ux, Uf, Vout.  Replicates: coeff->grid (einsum, pad, ifftshift, slice,
// irfft2 backward-norm) and grid->sph (rfft2, Vo contraction, .real).
// ---------------------------------------------------------------------------
__global__ __launch_bounds__(256) void precompute_C(
    const float* __restrict__ Ux_re, const float* __restrict__ Ux_im,
    const float* __restrict__ Uf_re, const float* __restrict__ Uf_im,
    const float* __restrict__ Vo_re, const float* __restrict__ Vo_im,
    float* __restrict__ CT) {
  __shared__ float G[2][729];   // G[0]=Gx[p][a*9+b], G[1]=Gf[q][a*9+b]
  __shared__ float TL[729];     // T[(a*9+b)*9 + d]
  const int t0 = threadIdx.x;

  // Phase A: Gx / Gf
  for (int t = t0; t < 1458; t += 256) {
    const int which = t / 729, idx = t % 729;
    const int p = idx / 81, ab = idx % 81, a = ab / 9, b = ab % 9;
    const float* Ure = which ? Uf_re : Ux_re;
    const float* Uim = which ? Uf_im : Ux_im;
    float g = 0.f;
    for (int v = 0; v < 5; ++v) {
      const int pc = (v + 4) % 9;           // ifftshift col source
      float hre = 0.f, him = 0.f;
      if (pc >= 2 && pc < 7) {              // inside pad window
        const int uc = pc - 2;
        for (int u = 0; u < 9; ++u) {
          const int pr = (u + 4) % 9;       // ifftshift row source
          if (pr < 2 || pr >= 7) continue;
          const int ur = pr - 2;
          const float re = Ure[p * 25 + ur * 5 + uc];
          const float im = Uim[p * 25 + ur * 5 + uc];
          const float ang = PI9 * (float)((u * a) % 9);   // ifft: e^{+i}
          const float c = cosf(ang), s = sinf(ang);
          hre += re * c - im * s;
          him += re * s + im * c;
        }
      }
      hre *= (1.f / 9.f); him *= (1.f / 9.f);
      if (v == 0) {
        g += hre;                            // irfft: Im of v=0 ignored
      } else {
        const float ang = PI9 * (float)((v * b) % 9);
        g += 2.f * (hre * cosf(ang) - him * sinf(ang));
      }
    }
    g *= (1.f / 9.f);
    G[which][p * 81 + ab] = g;
  }
  __syncthreads();

  // Phase B: T[a,b,d] = sum_{u<9,v<5} Re(e^{-i 2pi(ua+vb)/9} * Vo[u,v,d])
  for (int t = t0; t < 729; t += 256) {
    const int ab = t / 9, d = t % 9, a = ab / 9, b = ab % 9;
    float acc = 0.f;
    for (int u = 0; u < 9; ++u)
      for (int v = 0; v < 5; ++v) {
        const float ang = PI9 * (float)((u * a + v * b) % 9);
        acc += Vo_re[u * 45 + v * 9 + d] * cosf(ang)
             + Vo_im[u * 45 + v * 9 + d] * sinf(ang);
      }
    TL[ab * 9 + d] = acc;
  }
  __syncthreads();

  // Phase C: C[p,q,d] = sum_ab Gx[p,ab]*Gf[q,ab]*T[ab,d]  -> CT[d][p][q]
  for (int t = t0; t < 729; t += 256) {
    const int d = t / 81, rem = t % 81, p = rem / 9, q = rem % 9;
    float acc = 0.f;
    for (int ab = 0; ab < 81; ++ab)
      acc += G[0][p * 81 + ab] * G[1][q * 81 + ab] * TL[ab * 9 + d];
    CT[(d * 9 + p) * 12 + q] = acc;
  }
}

// ---------------------------------------------------------------------------
// Bin edges by destination node (fixed capacity 96 >> max Poisson(16) degree)
// ---------------------------------------------------------------------------
__global__ __launch_bounds__(256) void scatter_edges(
    const int* __restrict__ dst, int E, int* __restrict__ cnt,
    int* __restrict__ slots) {
  const int e = blockIdx.x * 256 + threadIdx.x;
  if (e < E) {
    const int d = dst[e];
    const int pos = atomicAdd(&cnt[d], 1);
    if (pos < 96) slots[d * 96 + pos] = e;
  }
}

// ---------------------------------------------------------------------------
// Edge MLP: w48[e][j] = (ssp(ssp(win@W1/sqrt8)@W2/8)@W3/8)[j] * s[j%3] / den
// Tiled f32; TE=64 edges per 128-thread block.
// ---------------------------------------------------------------------------
__global__ __launch_bounds__(128) void mlp_kernel(
    const float* __restrict__ win, const float* __restrict__ W1,
    const float* __restrict__ W2, const float* __restrict__ W3,
    const float* __restrict__ a_w, const float* __restrict__ den,
    float* __restrict__ w48) {
  __shared__ __align__(16) float ls_win[64 * 8];
  __shared__ __align__(16) float ls_W1[8 * 64];
  __shared__ __align__(16) float ls_W2[64 * 64];
  __shared__ __align__(16) float ls_W3[64 * 48];
  __shared__ __align__(16) float ls_h1[64 * 68];   // [k][e], padded
  __shared__ __align__(16) float ls_h2[64 * 68];
  const int t = threadIdx.x;
  const int e0 = blockIdx.x * 64;

  const float invden = 1.f / den[0];
  const float sc3[3] = {a_w[0] * invden, a_w[9 + 1] * invden, a_w[18 + 4] * invden};
  const float rs8 = 0.35355339059327373f;  // 1/sqrt(8)

  { const float4* s = (const float4*)(win + (size_t)e0 * 8);
    ((float4*)ls_win)[t] = s[t]; }
  { float4 v = ((const float4*)W1)[t];
    v.x *= rs8; v.y *= rs8; v.z *= rs8; v.w *= rs8;
    ((float4*)ls_W1)[t] = v; }
  for (int i = t; i < 1024; i += 128) {
    float4 v = ((const float4*)W2)[i];
    v.x *= 0.125f; v.y *= 0.125f; v.z *= 0.125f; v.w *= 0.125f;
    ((float4*)ls_W2)[i] = v;
  }
  for (int i = t; i < 3072; i += 128) {
    const int j = i % 48;
    ls_W3[i] = W3[i] * (0.125f * sc3[j % 3]);
  }
  __syncthreads();

  const int et = t % 16, jt = t / 16;   // 16 e-tiles x 8 j-tiles
  const int eb = et * 4, j0 = jt * 8;

  // Stage 1: h1 = ssp(win @ W1s)
  {
    float acc[4][8];
#pragma unroll
    for (int i = 0; i < 4; ++i)
#pragma unroll
      for (int j = 0; j < 8; ++j) acc[i][j] = 0.f;
#pragma unroll
    for (int k = 0; k < 8; ++k) {
      const float4 wA = *(const float4*)&ls_W1[k * 64 + j0];
      const float4 wB = *(const float4*)&ls_W1[k * 64 + j0 + 4];
      const float wj[8] = {wA.x, wA.y, wA.z, wA.w, wB.x, wB.y, wB.z, wB.w};
      const float a0 = ls_win[(eb + 0) * 8 + k];
      const float a1 = ls_win[(eb + 1) * 8 + k];
      const float a2 = ls_win[(eb + 2) * 8 + k];
      const float a3 = ls_win[(eb + 3) * 8 + k];
#pragma unroll
      for (int j = 0; j < 8; ++j) {
        acc[0][j] += a0 * wj[j];
        acc[1][j] += a1 * wj[j];
        acc[2][j] += a2 * wj[j];
        acc[3][j] += a3 * wj[j];
      }
    }
#pragma unroll
    for (int j = 0; j < 8; ++j) {
      float4 v = make_float4(ssp_f(acc[0][j]), ssp_f(acc[1][j]),
                             ssp_f(acc[2][j]), ssp_f(acc[3][j]));
      *(float4*)&ls_h1[(j0 + j) * 68 + eb] = v;
    }
  }
  __syncthreads();

  // Stage 2: h2 = ssp(h1 @ W2s)
  {
    float acc[4][8];
#pragma unroll
    for (int i = 0; i < 4; ++i)
#pragma unroll
      for (int j = 0; j < 8; ++j) acc[i][j] = 0.f;
#pragma unroll 4
    for (int k = 0; k < 64; ++k) {
      const float4 hv = *(const float4*)&ls_h1[k * 68 + eb];
      const float4 wA = *(const float4*)&ls_W2[k * 64 + j0];
      const float4 wB = *(const float4*)&ls_W2[k * 64 + j0 + 4];
      const float wj[8] = {wA.x, wA.y, wA.z, wA.w, wB.x, wB.y, wB.z, wB.w};
#pragma unroll
      for (int j = 0; j < 8; ++j) {
        acc[0][j] += hv.x * wj[j];
        acc[1][j] += hv.y * wj[j];
        acc[2][j] += hv.z * wj[j];
        acc[3][j] += hv.w * wj[j];
      }
    }
#pragma unroll
    for (int j = 0; j < 8; ++j) {
      float4 v = make_float4(ssp_f(acc[0][j]), ssp_f(acc[1][j]),
                             ssp_f(acc[2][j]), ssp_f(acc[3][j]));
      *(float4*)&ls_h2[(j0 + j) * 68 + eb] = v;
    }
  }
  __syncthreads();

  // Stage 3: w48 = h2 @ W3s  (scales folded into W3s)
  {
    const int j1 = jt * 6;
    float acc[4][6];
#pragma unroll
    for (int i = 0; i < 4; ++i)
#pragma unroll
      for (int j = 0; j < 6; ++j) acc[i][j] = 0.f;
#pragma unroll 4
    for (int k = 0; k < 64; ++k) {
      const float4 hv = *(const float4*)&ls_h2[k * 68 + eb];
      const float* wr = &ls_W3[k * 48 + j1];
#pragma unroll
      for (int j = 0; j < 6; ++j) {
        const float w = wr[j];
        acc[0][j] += hv.x * w;
        acc[1][j] += hv.y * w;
        acc[2][j] += hv.z * w;
        acc[3][j] += hv.w * w;
      }
    }
#pragma unroll
    for (int i = 0; i < 4; ++i)
#pragma unroll
      for (int j = 0; j < 6; ++j)
        w48[(size_t)(e0 + eb + i) * 48 + j1 + j] = acc[i][j];
  }
}

// ---------------------------------------------------------------------------
// Per-node message build + reduce (no atomics).
// msg[m,d] = sum_p x[src,m,p] * Me[p,d],  Me[p,d] = sum_q f[q] * C[p,q,d]
// out[n,m,d] = sum_edges msg * w48[e, m*3+l(d)]
// ---------------------------------------------------------------------------
__global__ __launch_bounds__(256) void node_kernel(
    const float* __restrict__ x, const float* __restrict__ filt,
    const int* __restrict__ src_idx, const int* __restrict__ cnt,
    const int* __restrict__ slots, const float* __restrict__ w48,
    const float* __restrict__ CT, float* __restrict__ out) {
  __shared__ __align__(16) float Cs[972];     // [d][p][q pad 12]
  __shared__ __align__(16) float fs[12];
  __shared__ __align__(16) float xs[16 * 12]; // [m][p pad 12]
  __shared__ __align__(16) float MeT[9 * 12]; // [d][p pad 12]
  __shared__ __align__(16) float ws48[48];
  const int t = threadIdx.x;
  const int n = blockIdx.x;

  for (int i = t; i < 972; i += 256) Cs[i] = CT[i];

  int deg = cnt[n];
  if (deg > 96) deg = 96;

  float acc = 0.f;
  const int m = t / 9, d = t % 9;                       // valid when t<144
  const int l = (d == 0) ? 0 : ((d < 4) ? 1 : 2);
  const int wcol = m * 3 + l;

  for (int i = 0; i < deg; ++i) {
    const int e = slots[n * 96 + i];
    const int s = src_idx[e];
    if (t < 9) {
      fs[t] = filt[(size_t)e * 9 + t];
    } else if (t >= 16 && t < 160) {
      const int ii = t - 16;
      xs[(ii / 9) * 12 + (ii % 9)] = x[(size_t)s * 144 + ii];
    } else if (t >= 160 && t < 208) {
      ws48[t - 160] = w48[(size_t)e * 48 + (t - 160)];
    }
    __syncthreads();
    if (t < 81) {
      const int dd = t / 9, p = t % 9;
      const float* c = &Cs[(dd * 9 + p) * 12];
      const float4 c0 = *(const float4*)c;
      const float4 c1 = *(const float4*)(c + 4);
      const float4 f0 = *(const float4*)fs;
      const float4 f1 = *(const float4*)(fs + 4);
      float me = c0.x * f0.x + c0.y * f0.y + c0.z * f0.z + c0.w * f0.w
               + c1.x * f1.x + c1.y * f1.y + c1.z * f1.z + c1.w * f1.w
               + c[8] * fs[8];
      MeT[dd * 12 + p] = me;
    }
    __syncthreads();
    if (t < 144) {
      const float* xr = &xs[m * 12];
      const float* mr = &MeT[d * 12];
      const float4 x0 = *(const float4*)xr;
      const float4 x1 = *(const float4*)(xr + 4);
      const float4 m0 = *(const float4*)mr;
      const float4 m1 = *(const float4*)(mr + 4);
      float msg = x0.x * m0.x + x0.y * m0.y + x0.z * m0.z + x0.w * m0.w
                + x1.x * m1.x + x1.y * m1.y + x1.z * m1.z + x1.w * m1.w
                + xr[8] * mr[8];
      acc += msg * ws48[wcol];
    }
    __syncthreads();
  }
  if (t < 144) out[(size_t)n * 144 + t] = acc;
}

// ---------------------------------------------------------------------------
extern "C" void kernel_launch(void* const* d_in, const int* in_sizes, int n_in,
                              void* d_out, int out_size, void* d_ws, size_t ws_size,
                              hipStream_t stream) {
  const float* x      = (const float*)d_in[0];
  const float* filt   = (const float*)d_in[1];
  const float* win    = (const float*)d_in[2];
  const int*   eidx   = (const int*)d_in[3];
  const float* Ux_re  = (const float*)d_in[4];
  const float* Ux_im  = (const float*)d_in[5];
  const float* Uf_re  = (const float*)d_in[6];
  const float* Uf_im  = (const float*)d_in[7];
  const float* Vo_re  = (const float*)d_in[8];
  const float* Vo_im  = (const float*)d_in[9];
  const float* W1     = (const float*)d_in[10];
  const float* W2     = (const float*)d_in[11];
  const float* W3     = (const float*)d_in[12];
  const float* a_w    = (const float*)d_in[13];
  const float* den    = (const float*)d_in[14];
  float* out = (float*)d_out;

  const int N = in_sizes[0] / 144;          // 10000
  const int E = in_sizes[3] / 2;            // 160000
  const int* dst = eidx;                    // edge_idx[0]
  const int* src = eidx + E;                // edge_idx[1]

  char* wsb = (char*)d_ws;
  float* CT   = (float*)wsb;                                  // 972 f
  int*   cnt  = (int*)(wsb + 4096);                           // N ints
  int*   slot = (int*)(wsb + 4096 + 40960);                   // N*96 ints
  float* w48  = (float*)(wsb + 4096 + 40960 + (size_t)N * 96 * 4);  // E*48 f

  hipMemsetAsync(cnt, 0, (size_t)N * sizeof(int), stream);
  precompute_C<<<1, 256, 0, stream>>>(Ux_re, Ux_im, Uf_re, Uf_im, Vo_re, Vo_im, CT);
  scatter_edges<<<(E + 255) / 256, 256, 0, stream>>>(dst, E, cnt, slot);
  mlp_kernel<<<E / 64, 128, 0, stream>>>(win, W1, W2, W3, a_w, den, w48);
  node_kernel<<<N, 256, 0, stream>>>(x, filt, src, cnt, slot, w48, CT, out);
}

// Round 2
// 214.543 us; speedup vs baseline: 2.1526x; 2.1526x over previous
//
#include <hip/hip_runtime.h>
#include <math.h>

#define PI9 (2.0f * 3.14159265358979323846f / 9.0f)

__device__ __forceinline__ float ssp_f(float x) {
  // softplus(x) - ln2, stable: max(x,0) + log1p(exp(-|x|)) - ln2
  const float ax = fabsf(x);
  const float t = __expf(-ax);
  return fmaxf(x, 0.f) + __logf(1.f + t) - 0.69314718f;
}

// ---------------------------------------------------------------------------
// Precompute C[p,q,d] stored transposed as CT[d][p][q pad 12].
// ---------------------------------------------------------------------------
__global__ __launch_bounds__(256) void precompute_C(
    const float* __restrict__ Ux_re, const float* __restrict__ Ux_im,
    const float* __restrict__ Uf_re, const float* __restrict__ Uf_im,
    const float* __restrict__ Vo_re, const float* __restrict__ Vo_im,
    float* __restrict__ CT) {
  __shared__ float G[2][729];   // G[0]=Gx[p][a*9+b], G[1]=Gf[q][a*9+b]
  __shared__ float TL[729];     // T[(a*9+b)*9 + d]
  const int t0 = threadIdx.x;

  for (int t = t0; t < 1458; t += 256) {
    const int which = t / 729, idx = t % 729;
    const int p = idx / 81, ab = idx % 81, a = ab / 9, b = ab % 9;
    const float* Ure = which ? Uf_re : Ux_re;
    const float* Uim = which ? Uf_im : Ux_im;
    float g = 0.f;
    for (int v = 0; v < 5; ++v) {
      const int pc = (v + 4) % 9;
      float hre = 0.f, him = 0.f;
      if (pc >= 2 && pc < 7) {
        const int uc = pc - 2;
        for (int u = 0; u < 9; ++u) {
          const int pr = (u + 4) % 9;
          if (pr < 2 || pr >= 7) continue;
          const int ur = pr - 2;
          const float re = Ure[p * 25 + ur * 5 + uc];
          const float im = Uim[p * 25 + ur * 5 + uc];
          const float ang = PI9 * (float)((u * a) % 9);
          const float c = cosf(ang), s = sinf(ang);
          hre += re * c - im * s;
          him += re * s + im * c;
        }
      }
      hre *= (1.f / 9.f); him *= (1.f / 9.f);
      if (v == 0) {
        g += hre;
      } else {
        const float ang = PI9 * (float)((v * b) % 9);
        g += 2.f * (hre * cosf(ang) - him * sinf(ang));
      }
    }
    g *= (1.f / 9.f);
    G[which][p * 81 + ab] = g;
  }
  __syncthreads();

  for (int t = t0; t < 729; t += 256) {
    const int ab = t / 9, d = t % 9, a = ab / 9, b = ab % 9;
    float acc = 0.f;
    for (int u = 0; u < 9; ++u)
      for (int v = 0; v < 5; ++v) {
        const float ang = PI9 * (float)((u * a + v * b) % 9);
        acc += Vo_re[u * 45 + v * 9 + d] * cosf(ang)
             + Vo_im[u * 45 + v * 9 + d] * sinf(ang);
      }
    TL[ab * 9 + d] = acc;
  }
  __syncthreads();

  for (int t = t0; t < 972; t += 256) {
    const int d = t / 108, rem = t % 108, p = rem / 12, q = rem % 12;
    if (p < 9) {
      float acc = 0.f;
      if (q < 9) {
        for (int ab = 0; ab < 81; ++ab)
          acc += G[0][p * 81 + ab] * G[1][q * 81 + ab] * TL[ab * 9 + d];
      }
      CT[(d * 9 + p) * 12 + q] = acc;   // zero padding lanes q=9..11
    }
  }
}

// ---------------------------------------------------------------------------
__global__ __launch_bounds__(256) void scatter_edges(
    const int* __restrict__ dst, int E, int* __restrict__ cnt,
    int* __restrict__ slots) {
  const int e = blockIdx.x * 256 + threadIdx.x;
  if (e < E) {
    const int d = dst[e];
    const int pos = atomicAdd(&cnt[d], 1);
    if (pos < 96) slots[d * 96 + pos] = e;
  }
}

// ---------------------------------------------------------------------------
// MLP: one thread per edge, all-register, weights via uniform L1-resident
// loads. w48[e][j] = MLP(win[e])[j] * sc[j%3]   (sc = a_w diag / denominator)
// ---------------------------------------------------------------------------
__global__ __launch_bounds__(256) void mlp_kernel(
    const float* __restrict__ win, const float* __restrict__ W1,
    const float* __restrict__ W2, const float* __restrict__ W3,
    const float* __restrict__ a_w, const float* __restrict__ den,
    float* __restrict__ w48) {
  const int e = blockIdx.x * 256 + threadIdx.x;
  const float invden = 1.f / den[0];
  const float sc[3] = {a_w[0] * invden, a_w[10] * invden, a_w[22] * invden};
  const float rs8 = 0.35355339059327373f;  // 1/sqrt(8)

  float in[8];
  {
    const float4 a = *(const float4*)(win + (size_t)e * 8);
    const float4 b = *(const float4*)(win + (size_t)e * 8 + 4);
    in[0] = a.x * rs8; in[1] = a.y * rs8; in[2] = a.z * rs8; in[3] = a.w * rs8;
    in[4] = b.x * rs8; in[5] = b.y * rs8; in[6] = b.z * rs8; in[7] = b.w * rs8;
  }

  // Stage 1 (fully unrolled so h1 indexing stays static): h1 = ssp(in@W1)/8
  float h1[64];
#pragma unroll
  for (int jb = 0; jb < 8; ++jb) {
    float acc[8];
#pragma unroll
    for (int j = 0; j < 8; ++j) acc[j] = 0.f;
#pragma unroll
    for (int k = 0; k < 8; ++k) {
      const float4 wa = *(const float4*)(W1 + k * 64 + jb * 8);
      const float4 wb = *(const float4*)(W1 + k * 64 + jb * 8 + 4);
      acc[0] = fmaf(in[k], wa.x, acc[0]);
      acc[1] = fmaf(in[k], wa.y, acc[1]);
      acc[2] = fmaf(in[k], wa.z, acc[2]);
      acc[3] = fmaf(in[k], wa.w, acc[3]);
      acc[4] = fmaf(in[k], wb.x, acc[4]);
      acc[5] = fmaf(in[k], wb.y, acc[5]);
      acc[6] = fmaf(in[k], wb.z, acc[6]);
      acc[7] = fmaf(in[k], wb.w, acc[7]);
    }
#pragma unroll
    for (int j = 0; j < 8; ++j) h1[jb * 8 + j] = ssp_f(acc[j]) * 0.125f;
  }

  // Stages 2+3 interleaved; jb loop rolled (keeps code small), k loop
  // unrolled (keeps h1 indexing static).
  float acc48[48];
#pragma unroll
  for (int o = 0; o < 48; ++o) acc48[o] = 0.f;

#pragma unroll 1
  for (int jb = 0; jb < 8; ++jb) {
    float a2[8];
#pragma unroll
    for (int j = 0; j < 8; ++j) a2[j] = 0.f;
    const float* w2p = W2 + jb * 8;
#pragma unroll
    for (int k = 0; k < 64; ++k) {
      const float hk = h1[k];
      const float4 wa = *(const float4*)(w2p + k * 64);
      const float4 wb = *(const float4*)(w2p + k * 64 + 4);
      a2[0] = fmaf(hk, wa.x, a2[0]);
      a2[1] = fmaf(hk, wa.y, a2[1]);
      a2[2] = fmaf(hk, wa.z, a2[2]);
      a2[3] = fmaf(hk, wa.w, a2[3]);
      a2[4] = fmaf(hk, wb.x, a2[4]);
      a2[5] = fmaf(hk, wb.y, a2[5]);
      a2[6] = fmaf(hk, wb.z, a2[6]);
      a2[7] = fmaf(hk, wb.w, a2[7]);
    }
#pragma unroll
    for (int jj = 0; jj < 8; ++jj) {
      const float h2 = ssp_f(a2[jj]) * 0.125f;
      const float* w3r = W3 + (jb * 8 + jj) * 48;
#pragma unroll
      for (int ob = 0; ob < 12; ++ob) {
        const float4 w3 = *(const float4*)(w3r + ob * 4);
        acc48[ob * 4 + 0] = fmaf(h2, w3.x, acc48[ob * 4 + 0]);
        acc48[ob * 4 + 1] = fmaf(h2, w3.y, acc48[ob * 4 + 1]);
        acc48[ob * 4 + 2] = fmaf(h2, w3.z, acc48[ob * 4 + 2]);
        acc48[ob * 4 + 3] = fmaf(h2, w3.w, acc48[ob * 4 + 3]);
      }
    }
  }

  float* outp = w48 + (size_t)e * 48;
#pragma unroll
  for (int ob = 0; ob < 12; ++ob) {
    float4 v;
    v.x = acc48[ob * 4 + 0] * sc[(ob * 4 + 0) % 3];
    v.y = acc48[ob * 4 + 1] * sc[(ob * 4 + 1) % 3];
    v.z = acc48[ob * 4 + 2] * sc[(ob * 4 + 2) % 3];
    v.w = acc48[ob * 4 + 3] * sc[(ob * 4 + 3) % 3];
    *(float4*)(outp + ob * 4) = v;
  }
}

// ---------------------------------------------------------------------------
// Node kernel v2: block per node, 4 waves; each wave owns every 4th edge,
// builds Me in its private LDS slab (in-order DS pipe -> no block barriers),
// C read from global (L1-resident).  Lane = (m = l&15, K = l>>4);
// d-slots per lane: d=K, d=K+4, and d=8 for K==0.
// ---------------------------------------------------------------------------
__global__ __launch_bounds__(256) void node_kernel(
    const float* __restrict__ x, const float* __restrict__ filt,
    const int* __restrict__ src_idx, const int* __restrict__ cnt,
    const int* __restrict__ slots, const float* __restrict__ w48,
    const float* __restrict__ CT, float* __restrict__ out) {
  __shared__ float MeT[4][9 * 12];     // per-wave [d][p pad 12]
  __shared__ float red[4][64][3];
  const int t = threadIdx.x;
  const int w = t >> 6, l = t & 63;
  const int n = blockIdx.x;

  int deg = cnt[n];
  if (deg > 96) deg = 96;

  const int m = l & 15, K = l >> 4;
  const int wc0 = m * 3 + ((K == 0) ? 0 : 1);  // l(d) for d=K
  const int wc12 = m * 3 + 2;                  // l(d) for d in 4..8
  // Me entry assignment: entry0 = l (always), entry1 = 64+l (l<17)
  const int dd0 = l / 9, p0 = l % 9;
  const int dd1 = (l + 64) / 9, p1 = (l + 64) % 9;

  float a0 = 0.f, a1 = 0.f, a2v = 0.f;

  for (int i = w; i < deg; i += 4) {
    const int e = slots[n * 96 + i];
    const int s = src_idx[e];

    // x row for this lane's m (reused by all d-slots)
    float xr[9];
#pragma unroll
    for (int p = 0; p < 9; ++p) xr[p] = x[(size_t)s * 144 + m * 9 + p];

    // filter coeffs (wave-uniform address -> scalar/broadcast loads)
    float f[9];
#pragma unroll
    for (int q = 0; q < 9; ++q) f[q] = filt[(size_t)e * 9 + q];

    // factors
    const float w0 = w48[(size_t)e * 48 + wc0];
    const float w12 = w48[(size_t)e * 48 + wc12];

    // Me entries: me[d][p] = sum_q CT[(d*9+p)*12+q] * f[q]
    {
      const float* c0 = CT + (dd0 * 9 + p0) * 12;
      const float4 ca = *(const float4*)c0;
      const float4 cb = *(const float4*)(c0 + 4);
      float me = ca.x * f[0] + ca.y * f[1] + ca.z * f[2] + ca.w * f[3]
               + cb.x * f[4] + cb.y * f[5] + cb.z * f[6] + cb.w * f[7]
               + c0[8] * f[8];
      MeT[w][dd0 * 12 + p0] = me;
    }
    if (l < 17) {
      const float* c0 = CT + (dd1 * 9 + p1) * 12;
      const float4 ca = *(const float4*)c0;
      const float4 cb = *(const float4*)(c0 + 4);
      float me = ca.x * f[0] + ca.y * f[1] + ca.z * f[2] + ca.w * f[3]
               + cb.x * f[4] + cb.y * f[5] + cb.z * f[6] + cb.w * f[7]
               + c0[8] * f[8];
      MeT[w][dd1 * 12 + p1] = me;
    }
    __builtin_amdgcn_wave_barrier();   // keep DS write->read order (in-order pipe)

    // msg for this lane's d-slots
    {
      const float* mr = &MeT[w][K * 12];
      const float4 m0 = *(const float4*)mr;
      const float4 m1 = *(const float4*)(mr + 4);
      float msg = xr[0] * m0.x + xr[1] * m0.y + xr[2] * m0.z + xr[3] * m0.w
                + xr[4] * m1.x + xr[5] * m1.y + xr[6] * m1.z + xr[7] * m1.w
                + xr[8] * mr[8];
      a0 = fmaf(msg, w0, a0);
    }
    {
      const float* mr = &MeT[w][(K + 4) * 12];
      const float4 m0 = *(const float4*)mr;
      const float4 m1 = *(const float4*)(mr + 4);
      float msg = xr[0] * m0.x + xr[1] * m0.y + xr[2] * m0.z + xr[3] * m0.w
                + xr[4] * m1.x + xr[5] * m1.y + xr[6] * m1.z + xr[7] * m1.w
                + xr[8] * mr[8];
      a1 = fmaf(msg, w12, a1);
    }
    if (K == 0) {
      const float* mr = &MeT[w][8 * 12];
      const float4 m0 = *(const float4*)mr;
      const float4 m1 = *(const float4*)(mr + 4);
      float msg = xr[0] * m0.x + xr[1] * m0.y + xr[2] * m0.z + xr[3] * m0.w
                + xr[4] * m1.x + xr[5] * m1.y + xr[6] * m1.z + xr[7] * m1.w
                + xr[8] * mr[8];
      a2v = fmaf(msg, w12, a2v);
    }
    __builtin_amdgcn_wave_barrier();   // before next iteration overwrites MeT
  }

  red[w][l][0] = a0;
  red[w][l][1] = a1;
  red[w][l][2] = a2v;
  __syncthreads();

  if (t < 144) {
    const int mm = t / 9, d = t % 9;
    int lane, slot;
    if (d < 4)      { lane = d * 16 + mm;       slot = 0; }
    else if (d < 8) { lane = (d - 4) * 16 + mm; slot = 1; }
    else            { lane = mm;                slot = 2; }
    const float sum = red[0][lane][slot] + red[1][lane][slot]
                    + red[2][lane][slot] + red[3][lane][slot];
    out[(size_t)n * 144 + t] = sum;
  }
}

// ---------------------------------------------------------------------------
extern "C" void kernel_launch(void* const* d_in, const int* in_sizes, int n_in,
                              void* d_out, int out_size, void* d_ws, size_t ws_size,
                              hipStream_t stream) {
  const float* x      = (const float*)d_in[0];
  const float* filt   = (const float*)d_in[1];
  const float* win    = (const float*)d_in[2];
  const int*   eidx   = (const int*)d_in[3];
  const float* Ux_re  = (const float*)d_in[4];
  const float* Ux_im  = (const float*)d_in[5];
  const float* Uf_re  = (const float*)d_in[6];
  const float* Uf_im  = (const float*)d_in[7];
  const float* Vo_re  = (const float*)d_in[8];
  const float* Vo_im  = (const float*)d_in[9];
  const float* W1     = (const float*)d_in[10];
  const float* W2     = (const float*)d_in[11];
  const float* W3     = (const float*)d_in[12];
  const float* a_w    = (const float*)d_in[13];
  const float* den    = (const float*)d_in[14];
  float* out = (float*)d_out;

  const int N = in_sizes[0] / 144;          // 10000
  const int E = in_sizes[3] / 2;            // 160000
  const int* dst = eidx;                    // edge_idx[0]
  const int* src = eidx + E;                // edge_idx[1]

  char* wsb = (char*)d_ws;
  float* CT   = (float*)wsb;                                  // 972 f
  int*   cnt  = (int*)(wsb + 4096);                           // N ints
  int*   slot = (int*)(wsb + 4096 + 40960);                   // N*96 ints
  float* w48  = (float*)(wsb + 4096 + 40960 + (size_t)N * 96 * 4);  // E*48 f

  hipMemsetAsync(cnt, 0, (size_t)N * sizeof(int), stream);
  precompute_C<<<1, 256, 0, stream>>>(Ux_re, Ux_im, Uf_re, Uf_im, Vo_re, Vo_im, CT);
  scatter_edges<<<(E + 255) / 256, 256, 0, stream>>>(dst, E, cnt, slot);
  mlp_kernel<<<E / 256, 256, 0, stream>>>(win, W1, W2, W3, a_w, den, w48);
  node_kernel<<<N, 256, 0, stream>>>(x, filt, src, cnt, slot, w48, CT, out);
}

// Round 3
// 137.162 us; speedup vs baseline: 3.3670x; 1.5642x over previous
//
#include <hip/hip_runtime.h>
#include <math.h>

#define PI9 (2.0f * 3.14159265358979323846f / 9.0f)

typedef float f32x4 __attribute__((ext_vector_type(4)));
typedef unsigned short us8 __attribute__((ext_vector_type(8)));
typedef __bf16 bf16x8 __attribute__((ext_vector_type(8)));

__device__ __forceinline__ float ssp_f(float x) {
  const float ax = fabsf(x);
  const float t = __expf(-ax);
  return fmaxf(x, 0.f) + __logf(1.f + t) - 0.69314718f;
}

__device__ __forceinline__ unsigned short f2bf(float f) {
  unsigned int u = __float_as_uint(f);
  unsigned int r = (u + 0x7FFFu + ((u >> 16) & 1u)) >> 16;
  return (unsigned short)r;
}

// ---------------------------------------------------------------------------
// Precompute C[p,q,d] -> CT[d][p][q pad 12].  Grid = 9 blocks (one per d);
// each block redundantly builds G (both), TL in LDS, then its d-slice of C.
// Trig via 9-entry sincos table (angles are exact multiples of 2pi/9).
// ---------------------------------------------------------------------------
__global__ __launch_bounds__(256) void precompute_C(
    const float* __restrict__ Ux_re, const float* __restrict__ Ux_im,
    const float* __restrict__ Uf_re, const float* __restrict__ Uf_im,
    const float* __restrict__ Vo_re, const float* __restrict__ Vo_im,
    float* __restrict__ CT) {
  __shared__ float G[2][729];   // G[0]=Gx[p][a*9+b], G[1]=Gf[q][a*9+b]
  __shared__ float TL[729];     // T[(a*9+b)*9 + d]
  __shared__ float cs9[9], sn9[9];
  const int t0 = threadIdx.x;

  if (t0 < 9) {
    float s, c;
    __sincosf(PI9 * (float)t0, &s, &c);
    cs9[t0] = c; sn9[t0] = s;
  }
  __syncthreads();

  // Phase A: Gx / Gf.  Only v in {0,1,2} (pc 4,5,6) and u in {7,8,0,1,2}
  // survive the pad/shift windows.
  for (int t = t0; t < 1458; t += 256) {
    const int which = t / 729, idx = t % 729;
    const int p = idx / 81, ab = idx % 81, a = ab / 9, b = ab % 9;
    const float* Ure = which ? Uf_re : Ux_re;
    const float* Uim = which ? Uf_im : Ux_im;
    float g = 0.f;
#pragma unroll
    for (int v = 0; v < 3; ++v) {
      const int uc = v + 2;
      float hre = 0.f, him = 0.f;
#pragma unroll
      for (int ui = 0; ui < 5; ++ui) {
        const int u = (ui + 7) % 9;   // pr = (u+4)%9 in [2,7), ur = ui
        const float re = Ure[p * 25 + ui * 5 + uc];
        const float im = Uim[p * 25 + ui * 5 + uc];
        const int k = (u * a) % 9;
        const float c = cs9[k], s = sn9[k];
        hre += re * c - im * s;
        him += re * s + im * c;
      }
      hre *= (1.f / 9.f); him *= (1.f / 9.f);
      if (v == 0) {
        g += hre;
      } else {
        const int k = (v * b) % 9;
        g += 2.f * (hre * cs9[k] - him * sn9[k]);
      }
    }
    G[which][p * 81 + ab] = g * (1.f / 9.f);
  }
  __syncthreads();

  // Phase B: T[a,b,d]
  for (int t = t0; t < 729; t += 256) {
    const int ab = t / 9, d = t % 9, a = ab / 9, b = ab % 9;
    float acc = 0.f;
    for (int u = 0; u < 9; ++u)
      for (int v = 0; v < 5; ++v) {
        const int k = (u * a + v * b) % 9;
        acc += Vo_re[u * 45 + v * 9 + d] * cs9[k]
             + Vo_im[u * 45 + v * 9 + d] * sn9[k];
      }
    TL[ab * 9 + d] = acc;
  }
  __syncthreads();

  // Phase C: this block's d-slice
  const int d = blockIdx.x;
  if (t0 < 108) {
    const int p = t0 / 12, q = t0 % 12;
    float acc = 0.f;
    if (q < 9) {
      for (int ab = 0; ab < 81; ++ab)
        acc += G[0][p * 81 + ab] * G[1][q * 81 + ab] * TL[ab * 9 + d];
    }
    CT[(d * 9 + p) * 12 + q] = acc;
  }
}

// ---------------------------------------------------------------------------
__global__ __launch_bounds__(256) void scatter_edges(
    const int* __restrict__ dst, int E, int* __restrict__ cnt,
    int* __restrict__ slots) {
  const int e = blockIdx.x * 256 + threadIdx.x;
  if (e < E) {
    const int d = dst[e];
    const int pos = atomicAdd(&cnt[d], 1);
    if (pos < 96) slots[d * 96 + pos] = e;
  }
}

// ---------------------------------------------------------------------------
// MLP via bf16 MFMA.  Block = 256 thr (4 waves), 64 edges; wave owns 16.
// Stage1 (K=8) in f32 VALU -> H1 bf16 LDS (chunk-XOR-swizzled).
// Stage2: h1(16x64) @ W2s -> ssp -> H2 (LDS transpose).  Stage3: @ W3s.
// Scales folded: W1s *= 1/sqrt8; W2T *= 0.125; W3T *= 0.125*sc[j%3].
// ---------------------------------------------------------------------------
__global__ __launch_bounds__(256) void mlp_mfma(
    const float* __restrict__ win, const float* __restrict__ W1,
    const float* __restrict__ W2, const float* __restrict__ W3,
    const float* __restrict__ a_w, const float* __restrict__ den,
    float* __restrict__ w48) {
  __shared__ __align__(16) float W1s[8 * 64];
  __shared__ __align__(16) unsigned short W2T[64 * 64];
  __shared__ __align__(16) unsigned short W3T[48 * 64];
  __shared__ __align__(16) unsigned short H1[4][16 * 64];
  __shared__ __align__(16) unsigned short H2[4][16 * 64];
  const int t = threadIdx.x;

  const float invden = 1.f / den[0];
  const float sc0 = a_w[0] * invden, sc1 = a_w[10] * invden, sc2 = a_w[22] * invden;
  const float rs8 = 0.35355339059327373f;

  if (t < 128) {
    float4 v = ((const float4*)W1)[t];
    v.x *= rs8; v.y *= rs8; v.z *= rs8; v.w *= rs8;
    ((float4*)W1s)[t] = v;
  }
  for (int i = t; i < 4096; i += 256) {
    const int k = i >> 6, j = i & 63;
    W2T[j * 64 + ((((k >> 3) ^ (j & 7)) << 3)) + (k & 7)] = f2bf(W2[i] * 0.125f);
  }
  for (int i = t; i < 3072; i += 256) {
    const int k = i / 48, j = i % 48;
    const int jm = j % 3;
    const float s = (jm == 0) ? sc0 : ((jm == 1) ? sc1 : sc2);
    W3T[j * 64 + ((((k >> 3) ^ (j & 7)) << 3)) + (k & 7)] = f2bf(W3[i] * 0.125f * s);
  }
  __syncthreads();

  const int w = t >> 6, l = t & 63;
  const int er = l & 15, g = l >> 4;
  const int e = blockIdx.x * 64 + w * 16 + er;
  unsigned short* h1p = &H1[w][0];
  unsigned short* h2p = &H2[w][0];

  // ---- stage 1: h1 = ssp(win @ W1s), this lane: edge er, cols g*16..g*16+15
  float in8[8];
  {
    const float4 A = *(const float4*)(win + (size_t)e * 8);
    const float4 B = *(const float4*)(win + (size_t)e * 8 + 4);
    in8[0] = A.x; in8[1] = A.y; in8[2] = A.z; in8[3] = A.w;
    in8[4] = B.x; in8[5] = B.y; in8[6] = B.z; in8[7] = B.w;
  }
  float h[16];
#pragma unroll
  for (int c = 0; c < 16; ++c) h[c] = 0.f;
#pragma unroll
  for (int k = 0; k < 8; ++k) {
    const float* wr = &W1s[k * 64 + g * 16];
    const float4 w0 = *(const float4*)wr;
    const float4 w1 = *(const float4*)(wr + 4);
    const float4 w2 = *(const float4*)(wr + 8);
    const float4 w3 = *(const float4*)(wr + 12);
    const float ik = in8[k];
    h[0]  = fmaf(ik, w0.x, h[0]);  h[1]  = fmaf(ik, w0.y, h[1]);
    h[2]  = fmaf(ik, w0.z, h[2]);  h[3]  = fmaf(ik, w0.w, h[3]);
    h[4]  = fmaf(ik, w1.x, h[4]);  h[5]  = fmaf(ik, w1.y, h[5]);
    h[6]  = fmaf(ik, w1.z, h[6]);  h[7]  = fmaf(ik, w1.w, h[7]);
    h[8]  = fmaf(ik, w2.x, h[8]);  h[9]  = fmaf(ik, w2.y, h[9]);
    h[10] = fmaf(ik, w2.z, h[10]); h[11] = fmaf(ik, w2.w, h[11]);
    h[12] = fmaf(ik, w3.x, h[12]); h[13] = fmaf(ik, w3.y, h[13]);
    h[14] = fmaf(ik, w3.z, h[14]); h[15] = fmaf(ik, w3.w, h[15]);
  }
  us8 pk0, pk1;
#pragma unroll
  for (int jj = 0; jj < 8; ++jj) pk0[jj] = f2bf(ssp_f(h[jj]));
#pragma unroll
  for (int jj = 0; jj < 8; ++jj) pk1[jj] = f2bf(ssp_f(h[8 + jj]));
  *(us8*)&h1p[er * 64 + (((2 * g) ^ (er & 7)) << 3)] = pk0;
  *(us8*)&h1p[er * 64 + (((2 * g + 1) ^ (er & 7)) << 3)] = pk1;
  asm volatile("s_waitcnt lgkmcnt(0)" ::: "memory");
  __builtin_amdgcn_wave_barrier();

  // ---- stage 2: 8 MFMA (4 N-tiles x K=64)
  const us8 a0 = *(const us8*)&h1p[er * 64 + ((g ^ (er & 7)) << 3)];
  const us8 a1 = *(const us8*)&h1p[er * 64 + (((g + 4) ^ (er & 7)) << 3)];
  float hh[16];
#pragma unroll
  for (int nt = 0; nt < 4; ++nt) {
    const int j = nt * 16 + er;
    const us8 b0 = *(const us8*)&W2T[j * 64 + ((g ^ (j & 7)) << 3)];
    const us8 b1 = *(const us8*)&W2T[j * 64 + (((g + 4) ^ (j & 7)) << 3)];
    f32x4 acc = {0.f, 0.f, 0.f, 0.f};
    acc = __builtin_amdgcn_mfma_f32_16x16x32_bf16(
        __builtin_bit_cast(bf16x8, a0), __builtin_bit_cast(bf16x8, b0), acc, 0, 0, 0);
    acc = __builtin_amdgcn_mfma_f32_16x16x32_bf16(
        __builtin_bit_cast(bf16x8, a1), __builtin_bit_cast(bf16x8, b1), acc, 0, 0, 0);
#pragma unroll
    for (int r = 0; r < 4; ++r) hh[nt * 4 + r] = ssp_f(acc[r]);
  }
  // transpose h2 through LDS: lane holds h2[e2 = g*4+r][k2 = nt*16+er]
#pragma unroll
  for (int nt = 0; nt < 4; ++nt)
#pragma unroll
    for (int r = 0; r < 4; ++r) {
      const int e2 = g * 4 + r;
      const int k2 = nt * 16 + er;
      h2p[e2 * 64 + ((((k2 >> 3) ^ (e2 & 7)) << 3)) + (k2 & 7)] = f2bf(hh[nt * 4 + r]);
    }
  asm volatile("s_waitcnt lgkmcnt(0)" ::: "memory");
  __builtin_amdgcn_wave_barrier();

  // ---- stage 3: 6 MFMA (3 N-tiles x K=64), scales pre-folded
  const us8 c0 = *(const us8*)&h2p[er * 64 + ((g ^ (er & 7)) << 3)];
  const us8 c1 = *(const us8*)&h2p[er * 64 + (((g + 4) ^ (er & 7)) << 3)];
  const int ebase = blockIdx.x * 64 + w * 16 + g * 4;
#pragma unroll
  for (int nt = 0; nt < 3; ++nt) {
    const int o = nt * 16 + er;
    const us8 b0 = *(const us8*)&W3T[o * 64 + ((g ^ (o & 7)) << 3)];
    const us8 b1 = *(const us8*)&W3T[o * 64 + (((g + 4) ^ (o & 7)) << 3)];
    f32x4 acc = {0.f, 0.f, 0.f, 0.f};
    acc = __builtin_amdgcn_mfma_f32_16x16x32_bf16(
        __builtin_bit_cast(bf16x8, c0), __builtin_bit_cast(bf16x8, b0), acc, 0, 0, 0);
    acc = __builtin_amdgcn_mfma_f32_16x16x32_bf16(
        __builtin_bit_cast(bf16x8, c1), __builtin_bit_cast(bf16x8, b1), acc, 0, 0, 0);
#pragma unroll
    for (int r = 0; r < 4; ++r)
      w48[(size_t)(ebase + r) * 48 + o] = acc[r];
  }
}

// ---------------------------------------------------------------------------
// Node kernel v3: 4 waves/node, 1 edge/wave/iter, T14 prefetch pipeline.
// filt/slots/src scalarized; x row staged coalesced (36 lanes float4->LDS).
// ---------------------------------------------------------------------------
__global__ __launch_bounds__(256) void node_kernel(
    const float* __restrict__ x, const float* __restrict__ filt,
    const int* __restrict__ src_idx, const int* __restrict__ cnt,
    const int* __restrict__ slots, const float* __restrict__ w48,
    const float* __restrict__ CT, float* __restrict__ out) {
  __shared__ __align__(16) float Cs[972];
  __shared__ __align__(16) float xsl[4][144];
  __shared__ __align__(16) float MeT[4][9 * 12];
  __shared__ __align__(16) float red[4][64][3];
  const int t = threadIdx.x, w = t >> 6, l = t & 63;
  const int n = blockIdx.x;

  for (int i = t; i < 972; i += 256) Cs[i] = CT[i];
  __syncthreads();

  int deg = cnt[n];
  if (deg > 96) deg = 96;

  const int m = l & 15, K = l >> 4;
  const int wc0 = m * 3 + ((K == 0) ? 0 : 1);
  const int wc12 = m * 3 + 2;
  const int dd0 = l / 9, p0 = l % 9;
  const int dd1 = (l + 64) / 9, p1 = (l + 64) % 9;

  float a0 = 0.f, a1 = 0.f, a2v = 0.f;

  int i = w;
  if (i < deg) {
    int e = __builtin_amdgcn_readfirstlane(slots[n * 96 + i]);
    int s = __builtin_amdgcn_readfirstlane(src_idx[e]);
    float4 xv = make_float4(0.f, 0.f, 0.f, 0.f);
    if (l < 36) xv = *(const float4*)(x + (size_t)s * 144 + l * 4);
    float f[9];
#pragma unroll
    for (int q = 0; q < 9; ++q) f[q] = filt[(size_t)e * 9 + q];
    float wv0 = w48[(size_t)e * 48 + wc0];
    float wv12 = w48[(size_t)e * 48 + wc12];

    while (true) {
      // land current x row into this wave's slab
      if (l < 36) *(float4*)&xsl[w][l * 4] = xv;

      // prefetch next edge (overlaps with compute below)
      const int inext = i + 4;
      const bool more = inext < deg;
      float4 xv_n = make_float4(0.f, 0.f, 0.f, 0.f);
      float f_n[9];
      float wn0 = 0.f, wn12 = 0.f;
      if (more) {
        const int e_n = __builtin_amdgcn_readfirstlane(slots[n * 96 + inext]);
        const int s_n = __builtin_amdgcn_readfirstlane(src_idx[e_n]);
        if (l < 36) xv_n = *(const float4*)(x + (size_t)s_n * 144 + l * 4);
#pragma unroll
        for (int q = 0; q < 9; ++q) f_n[q] = filt[(size_t)e_n * 9 + q];
        wn0 = w48[(size_t)e_n * 48 + wc0];
        wn12 = w48[(size_t)e_n * 48 + wc12];
      } else {
#pragma unroll
        for (int q = 0; q < 9; ++q) f_n[q] = 0.f;
      }

      asm volatile("s_waitcnt lgkmcnt(0)" ::: "memory");
      __builtin_amdgcn_wave_barrier();

      // Me[d][p] = sum_q Cs[(d*9+p)*12+q] * f[q]
      {
        const float* c = &Cs[(dd0 * 9 + p0) * 12];
        const float4 ca = *(const float4*)c;
        const float4 cb = *(const float4*)(c + 4);
        float me = ca.x * f[0] + ca.y * f[1] + ca.z * f[2] + ca.w * f[3]
                 + cb.x * f[4] + cb.y * f[5] + cb.z * f[6] + cb.w * f[7]
                 + c[8] * f[8];
        MeT[w][dd0 * 12 + p0] = me;
      }
      if (l < 17) {
        const float* c = &Cs[(dd1 * 9 + p1) * 12];
        const float4 ca = *(const float4*)c;
        const float4 cb = *(const float4*)(c + 4);
        float me = ca.x * f[0] + ca.y * f[1] + ca.z * f[2] + ca.w * f[3]
                 + cb.x * f[4] + cb.y * f[5] + cb.z * f[6] + cb.w * f[7]
                 + c[8] * f[8];
        MeT[w][dd1 * 12 + p1] = me;
      }
      asm volatile("s_waitcnt lgkmcnt(0)" ::: "memory");
      __builtin_amdgcn_wave_barrier();

      // msg for this lane's (m, d-slots)
      float xr[9];
#pragma unroll
      for (int p = 0; p < 9; ++p) xr[p] = xsl[w][m * 9 + p];
      {
        const float* mr = &MeT[w][K * 12];
        const float4 m0 = *(const float4*)mr;
        const float4 m1 = *(const float4*)(mr + 4);
        float msg = xr[0] * m0.x + xr[1] * m0.y + xr[2] * m0.z + xr[3] * m0.w
                  + xr[4] * m1.x + xr[5] * m1.y + xr[6] * m1.z + xr[7] * m1.w
                  + xr[8] * mr[8];
        a0 = fmaf(msg, wv0, a0);
      }
      {
        const float* mr = &MeT[w][(K + 4) * 12];
        const float4 m0 = *(const float4*)mr;
        const float4 m1 = *(const float4*)(mr + 4);
        float msg = xr[0] * m0.x + xr[1] * m0.y + xr[2] * m0.z + xr[3] * m0.w
                  + xr[4] * m1.x + xr[5] * m1.y + xr[6] * m1.z + xr[7] * m1.w
                  + xr[8] * mr[8];
        a1 = fmaf(msg, wv12, a1);
      }
      if (K == 0) {
        const float* mr = &MeT[w][8 * 12];
        const float4 m0 = *(const float4*)mr;
        const float4 m1 = *(const float4*)(mr + 4);
        float msg = xr[0] * m0.x + xr[1] * m0.y + xr[2] * m0.z + xr[3] * m0.w
                  + xr[4] * m1.x + xr[5] * m1.y + xr[6] * m1.z + xr[7] * m1.w
                  + xr[8] * mr[8];
        a2v = fmaf(msg, wv12, a2v);
      }
      __builtin_amdgcn_wave_barrier();

      if (!more) break;
      i = inext;
      xv = xv_n;
#pragma unroll
      for (int q = 0; q < 9; ++q) f[q] = f_n[q];
      wv0 = wn0; wv12 = wn12;
    }
  }

  red[w][l][0] = a0;
  red[w][l][1] = a1;
  red[w][l][2] = a2v;
  __syncthreads();

  if (t < 144) {
    const int mm = t / 9, d = t % 9;
    int lane, slot;
    if (d < 4)      { lane = d * 16 + mm;       slot = 0; }
    else if (d < 8) { lane = (d - 4) * 16 + mm; slot = 1; }
    else            { lane = mm;                slot = 2; }
    const float sum = red[0][lane][slot] + red[1][lane][slot]
                    + red[2][lane][slot] + red[3][lane][slot];
    out[(size_t)n * 144 + t] = sum;
  }
}

// ---------------------------------------------------------------------------
extern "C" void kernel_launch(void* const* d_in, const int* in_sizes, int n_in,
                              void* d_out, int out_size, void* d_ws, size_t ws_size,
                              hipStream_t stream) {
  const float* x      = (const float*)d_in[0];
  const float* filt   = (const float*)d_in[1];
  const float* win    = (const float*)d_in[2];
  const int*   eidx   = (const int*)d_in[3];
  const float* Ux_re  = (const float*)d_in[4];
  const float* Ux_im  = (const float*)d_in[5];
  const float* Uf_re  = (const float*)d_in[6];
  const float* Uf_im  = (const float*)d_in[7];
  const float* Vo_re  = (const float*)d_in[8];
  const float* Vo_im  = (const float*)d_in[9];
  const float* W1     = (const float*)d_in[10];
  const float* W2     = (const float*)d_in[11];
  const float* W3     = (const float*)d_in[12];
  const float* a_w    = (const float*)d_in[13];
  const float* den    = (const float*)d_in[14];
  float* out = (float*)d_out;

  const int N = in_sizes[0] / 144;          // 10000
  const int E = in_sizes[3] / 2;            // 160000
  const int* dst = eidx;                    // edge_idx[0]
  const int* src = eidx + E;                // edge_idx[1]

  char* wsb = (char*)d_ws;
  float* CT   = (float*)wsb;                                  // 972 f
  int*   cnt  = (int*)(wsb + 4096);                           // N ints
  int*   slot = (int*)(wsb + 4096 + 40960);                   // N*96 ints
  float* w48  = (float*)(wsb + 4096 + 40960 + (size_t)N * 96 * 4);  // E*48 f

  hipMemsetAsync(cnt, 0, (size_t)N * sizeof(int), stream);
  precompute_C<<<9, 256, 0, stream>>>(Ux_re, Ux_im, Uf_re, Uf_im, Vo_re, Vo_im, CT);
  scatter_edges<<<(E + 255) / 256, 256, 0, stream>>>(dst, E, cnt, slot);
  mlp_mfma<<<E / 64, 256, 0, stream>>>(win, W1, W2, W3, a_w, den, w48);
  node_kernel<<<N, 256, 0, stream>>>(x, filt, src, cnt, slot, w48, CT, out);
}